// Round 2
// baseline (647.931 us; speedup 1.0000x reference)
//
#include <hip/hip_runtime.h>

typedef unsigned short u16;
typedef __attribute__((ext_vector_type(8))) short s8;
typedef __attribute__((ext_vector_type(4))) float f4;

#define N_TRAJ 4096
#define TSTEPS 128
#define LATD   64
#define INPD   128

// bias offsets (floats)
#define OB1 0
#define OB2 128
#define UB1 192
#define UB2 320
#define RB1 384
#define RB2 512
#define NB1 576
#define NB2 704
#define TB1 832
#define TB2 960
#define DTS 1088
#define NBIAS 1216

// packed weight offsets (elements)
#define OFF_UG1 0
#define OFF_RG1 32768
#define OFF_NS1 65536
#define OFF_OD1 98304
#define OFF_UG2 106496
#define OFF_RG2 114688
#define OFF_NS2 122880
#define OFF_OD2 139264
#define OFF_TZ1 147456
#define OFF_TZ2 163840
#define PACK_ELEMS 180224

__device__ u16 g_pack[PACK_ELEMS];
__device__ float g_bias[NBIAS];

__device__ __forceinline__ float b2f(u16 u) {
    union { unsigned int i; float f; } v; v.i = ((unsigned int)u) << 16; return v.f;
}
__device__ __forceinline__ u16 f2b(float f) {
    unsigned int x = __float_as_uint(f);
    unsigned int r = (x + 0x7FFFu + ((x >> 16) & 1u)) >> 16;
    return (u16)r;
}
__device__ __forceinline__ int is_f32(const void* tps) {
    return (*(const unsigned int*)tps) == 0u;  // f32: bits(0.0f); bf16: 0x3C810000
}
__device__ __forceinline__ float rdany(const void* a, int i, int isf32) {
    return isf32 ? ((const float*)a)[i] : b2f(((const u16*)a)[i]);
}
__device__ __forceinline__ float sigm(float x) {
    x = fminf(fmaxf(x, -30.f), 30.f);
    float e = __expf(-x);
    return __builtin_amdgcn_rcpf(1.f + e);
}
__device__ __forceinline__ float tanh_(float x) {
    x = fminf(fmaxf(x, -15.f), 15.f);
    float e = __expf(-2.f * x);
    return (1.f - e) * __builtin_amdgcn_rcpf(1.f + e);
}

// A-fragment read from a [16][128] bf16 LDS tile (row stride 256B, XOR swizzled)
__device__ __forceinline__ s8 aread(const u16* buf, int lane, int ks) {
    int row = lane & 15;
    int b = (ks << 6) + ((lane >> 4) << 4);
    int off = (row << 8) + (b ^ ((row & 7) << 4));
    return *(const s8*)((const char*)buf + off);
}
__device__ __forceinline__ void hwrite(u16* buf, int rowt, int col, float v) {
    int off = (rowt << 8) + (((col << 1)) ^ ((rowt & 7) << 4));
    *(u16*)((char*)buf + off) = f2b(v);
}
__device__ __forceinline__ u16 sread(const u16* buf, int rowt, int col) {
    int off = (rowt << 8) + (((col << 1)) ^ ((rowt & 7) << 4));
    return *(const u16*)((const char*)buf + off);
}
// load 8 consecutive x elements as bf16, from either dtype
__device__ __forceinline__ s8 load_x8(const void* data, size_t elemIdx, int isf32) {
    s8 r;
    if (isf32) {
        const float* f = (const float*)data + elemIdx;
        f4 lo = *(const f4*)f;
        f4 hi = *(const f4*)(f + 4);
#pragma unroll
        for (int j = 0; j < 4; ++j) { r[j] = (short)f2b(lo[j]); r[4 + j] = (short)f2b(hi[j]); }
    } else {
        r = *(const s8*)((const u16*)data + elemIdx);
    }
    return r;
}

struct PackP {
    const void* src[10];
    const void* tps;
    int Kr[10], Nr[10], KS[10], sz[10];
};

__global__ __launch_bounds__(256) void repack_kernel(PackP p) {
    int gid = blockIdx.x * 256 + threadIdx.x;
    if (gid >= PACK_ELEMS) return;
    int isf32 = is_f32(p.tps);
    int idx = gid, m = 0, base = 0;
    while (m < 10 && idx >= p.sz[m]) { idx -= p.sz[m]; base += p.sz[m]; ++m; }
    if (m >= 10) return;
    int i = idx & 7;
    int l = (idx >> 3) & 63;
    int rest = idx >> 9;
    int ks = rest % p.KS[m];
    int nt = rest / p.KS[m];
    int k = ks * 32 + ((l >> 4) << 3) + i;
    int n = nt * 16 + (l & 15);
    u16 v = 0;
    if (k < p.Kr[m] && n < p.Nr[m]) v = f2b(rdany(p.src[m], k * p.Nr[m] + n, isf32));
    g_pack[base + idx] = v;
}

struct PrepP {
    const void *tps, *ob1, *ob2, *ub1, *ub2, *rb1, *rb2, *nb1, *nb2, *tb1, *tb2;
};

__global__ __launch_bounds__(256) void prep_bias(PrepP p) {
    int isf32 = is_f32(p.tps);
    int tid = threadIdx.x;
    for (int i = tid; i < 128; i += 256) {
        g_bias[OB1 + i] = (i < 100) ? rdany(p.ob1, i, isf32) : 0.f;
        g_bias[UB1 + i] = (i < 100) ? rdany(p.ub1, i, isf32) : 0.f;
        g_bias[RB1 + i] = (i < 100) ? rdany(p.rb1, i, isf32) : 0.f;
        g_bias[NB1 + i] = (i < 100) ? rdany(p.nb1, i, isf32) : 0.f;
        g_bias[TB1 + i] = (i < 100) ? rdany(p.tb1, i, isf32) : 0.f;
        g_bias[NB2 + i] = rdany(p.nb2, i, isf32);
        g_bias[TB2 + i] = rdany(p.tb2, i, isf32);
        g_bias[DTS + i] = (i == 0) ? -0.01f
                                   : (rdany(p.tps, 127 - i, isf32) - rdany(p.tps, 128 - i, isf32));
    }
    for (int i = tid; i < 64; i += 256) {
        g_bias[OB2 + i] = rdany(p.ob2, i, isf32);
        g_bias[UB2 + i] = rdany(p.ub2, i, isf32);
        g_bias[RB2 + i] = rdany(p.rb2, i, isf32);
    }
}

struct MainP {
    const void *data, *tps;
    void* out;
};

#define WLOAD(off, KSn, nt, ks) (*(const s8*)(pk + (off) + (((((nt) * (KSn)) + (ks)) << 6) + lane) * 8))
#define MFMA(a, b, c) __builtin_amdgcn_mfma_f32_16x16x32_bf16((a), (b), (c), 0, 0, 0)

__global__ __launch_bounds__(256, 1) void enc_main(MainP p) {
    __shared__ u16 s_x[2][2048];   // [16][128] bf16 swizzled, double buffered
    __shared__ u16 s_yc[2048];     // [y_mu | s] bf16 swizzled
    __shared__ u16 s_yc2[2048];    // [y_mu*r | s*r]
    __shared__ u16 s_hA[2048];     // h buffer (hode/hu/hns)
    __shared__ u16 s_hB[2048];     // hr
    __shared__ float s_ym[1024], s_yo[1024], s_sm[1024], s_u[1024];
    __shared__ float s_b[NBIAS];

    int tid = threadIdx.x, lane = tid & 63, w = tid >> 6;
    int btraj = blockIdx.x << 4;
    const u16* pk = g_pack;
    int isf32 = is_f32(p.tps);

    for (int i = tid; i < NBIAS; i += 256) s_b[i] = g_bias[i];
    for (int i = tid; i < 1024; i += 256) { s_ym[i] = 0.f; s_sm[i] = 0.f; }
    for (int i = tid; i < 2048; i += 256) s_yc[i] = 0;

    // per-wave weight fragments in registers
    s8 wu1[2][8], wr1[2][8], wn1[2][8], wo1[2][2], wn2[2][4];
    s8 wu2[4], wr2[4], wo2[4], wt1[2][4], wt2[2][4];
#pragma unroll
    for (int tt = 0; tt < 2; ++tt) {
        int nt = 2 * w + tt;
#pragma unroll
        for (int ks = 0; ks < 8; ++ks) {
            wu1[tt][ks] = WLOAD(OFF_UG1, 8, nt, ks);
            wr1[tt][ks] = WLOAD(OFF_RG1, 8, nt, ks);
            wn1[tt][ks] = WLOAD(OFF_NS1, 8, nt, ks);
        }
#pragma unroll
        for (int ks = 0; ks < 2; ++ks) wo1[tt][ks] = WLOAD(OFF_OD1, 2, nt, ks);
#pragma unroll
        for (int ks = 0; ks < 4; ++ks) {
            wn2[tt][ks] = WLOAD(OFF_NS2, 4, nt, ks);
            wt1[tt][ks] = WLOAD(OFF_TZ1, 4, nt, ks);
            wt2[tt][ks] = WLOAD(OFF_TZ2, 4, nt, ks);
        }
    }
#pragma unroll
    for (int ks = 0; ks < 4; ++ks) {
        wu2[ks] = WLOAD(OFF_UG2, 4, w, ks);
        wr2[ks] = WLOAD(OFF_RG2, 4, w, ks);
        wo2[ks] = WLOAD(OFF_OD2, 4, w, ks);
    }

    // prefetch x for step 0 (t = 127)
    int xrow = tid >> 4, xk = tid & 15;
    {
        s8 xr = load_x8(p.data, ((size_t)(btraj + xrow) * TSTEPS + 127) * INPD + (xk << 3), isf32);
        int off = (xrow << 8) + (((xk << 4)) ^ ((xrow & 7) << 4));
        *(s8*)((char*)s_x[0] + off) = xr;
    }
    __syncthreads();

    const f4 zero4 = {0.f, 0.f, 0.f, 0.f};

    for (int it = 0; it < TSTEPS; ++it) {
        int cur = it & 1;
        float dt = s_b[DTS + it];

        // prefetch next x
        s8 xnext;
        if (it < 127) {
            xnext = load_x8(p.data, ((size_t)(btraj + xrow) * TSTEPS + (126 - it)) * INPD + (xk << 3), isf32);
        }

        // ---- Phase A: ODE layer 1 (A = y from yc[0:64], K=64) ----
        {
            f4 ao[2] = {zero4, zero4};
            s8 a0 = aread(s_yc, lane, 0);
            s8 a1 = aread(s_yc, lane, 1);
#pragma unroll
            for (int tt = 0; tt < 2; ++tt) {
                ao[tt] = MFMA(a0, wo1[tt][0], ao[tt]);
                ao[tt] = MFMA(a1, wo1[tt][1], ao[tt]);
            }
#pragma unroll
            for (int tt = 0; tt < 2; ++tt) {
                int colb = ((2 * w + tt) << 4) + (lane & 15);
                float bias = s_b[OB1 + colb];
#pragma unroll
                for (int j = 0; j < 4; ++j) {
                    int rowt = ((lane >> 4) << 2) + j;
                    hwrite(s_hA, rowt, colb, tanh_(ao[tt][j] + bias));
                }
            }
        }
        __syncthreads();

        // ---- Phase B: ODE layer 2 -> y_ode; write into yc[0:64] ----
        {
            f4 ac = zero4;
#pragma unroll
            for (int ks = 0; ks < 4; ++ks) ac = MFMA(aread(s_hA, lane, ks), wo2[ks], ac);
            int col = (w << 4) + (lane & 15);
            float bias = s_b[OB2 + col];
#pragma unroll
            for (int j = 0; j < 4; ++j) {
                int rowt = ((lane >> 4) << 2) + j;
                float yo = s_ym[rowt * 64 + col] + (ac[j] + bias) * dt;
                s_yo[rowt * 64 + col] = yo;
                hwrite(s_yc, rowt, col, yo);
            }
        }
        __syncthreads();

        // ---- Phase C: u,r layer 1 (A = [y_ode|s|x], K=256) ----
        {
            f4 au[2] = {zero4, zero4}, ar[2] = {zero4, zero4};
#pragma unroll
            for (int ks = 0; ks < 8; ++ks) {
                s8 a = (ks < 4) ? aread(s_yc, lane, ks) : aread(s_x[cur], lane, ks - 4);
#pragma unroll
                for (int tt = 0; tt < 2; ++tt) {
                    au[tt] = MFMA(a, wu1[tt][ks], au[tt]);
                    ar[tt] = MFMA(a, wr1[tt][ks], ar[tt]);
                }
            }
#pragma unroll
            for (int tt = 0; tt < 2; ++tt) {
                int colb = ((2 * w + tt) << 4) + (lane & 15);
                float bu = s_b[UB1 + colb], br = s_b[RB1 + colb];
#pragma unroll
                for (int j = 0; j < 4; ++j) {
                    int rowt = ((lane >> 4) << 2) + j;
                    hwrite(s_hA, rowt, colb, tanh_(au[tt][j] + bu));
                    hwrite(s_hB, rowt, colb, tanh_(ar[tt][j] + br));
                }
            }
        }
        __syncthreads();

        // ---- Phase D: u,r layer 2; build yc2 = [y_mu*r | s*r] ----
        {
            f4 uac = zero4, rac = zero4;
#pragma unroll
            for (int ks = 0; ks < 4; ++ks) {
                uac = MFMA(aread(s_hA, lane, ks), wu2[ks], uac);
                rac = MFMA(aread(s_hB, lane, ks), wr2[ks], rac);
            }
            int col = (w << 4) + (lane & 15);
            float bu = s_b[UB2 + col], br = s_b[RB2 + col];
#pragma unroll
            for (int j = 0; j < 4; ++j) {
                int rowt = ((lane >> 4) << 2) + j;
                float uval = sigm(uac[j] + bu);
                float rval = sigm(rac[j] + br);
                s_u[rowt * 64 + col] = uval;
                float ymu = s_yo[rowt * 64 + col];
                float sv = s_sm[rowt * 64 + col];
                hwrite(s_yc2, rowt, col, ymu * rval);
                hwrite(s_yc2, rowt, 64 + col, sv * rval);
            }
        }
        __syncthreads();

        // ---- Phase E: ns layer 1 (A = [yc2 | x], K=256) ----
        {
            f4 an[2] = {zero4, zero4};
#pragma unroll
            for (int ks = 0; ks < 8; ++ks) {
                s8 a = (ks < 4) ? aread(s_yc2, lane, ks) : aread(s_x[cur], lane, ks - 4);
#pragma unroll
                for (int tt = 0; tt < 2; ++tt) an[tt] = MFMA(a, wn1[tt][ks], an[tt]);
            }
#pragma unroll
            for (int tt = 0; tt < 2; ++tt) {
                int colb = ((2 * w + tt) << 4) + (lane & 15);
                float bn = s_b[NB1 + colb];
#pragma unroll
                for (int j = 0; j < 4; ++j) {
                    int rowt = ((lane >> 4) << 2) + j;
                    hwrite(s_hA, rowt, colb, tanh_(an[tt][j] + bn));
                }
            }
        }
        __syncthreads();

        // ---- Phase F: ns layer 2 + state update ----
        {
            f4 fn[2] = {zero4, zero4};
#pragma unroll
            for (int ks = 0; ks < 4; ++ks) {
                s8 a = aread(s_hA, lane, ks);
#pragma unroll
                for (int tt = 0; tt < 2; ++tt) fn[tt] = MFMA(a, wn2[tt][ks], fn[tt]);
            }
            // store prefetched x into the other buffer
            if (it < 127) {
                int off = (xrow << 8) + (((xk << 4)) ^ ((xrow & 7) << 4));
                *(s8*)((char*)s_x[cur ^ 1] + off) = xnext;
            }
#pragma unroll
            for (int tt = 0; tt < 2; ++tt) {
                int colf = ((2 * w + tt) << 4) + (lane & 15);
                float bn = s_b[NB2 + colf];
                int c = colf & 63;
                bool hi = colf >= 64;
#pragma unroll
                for (int j = 0; j < 4; ++j) {
                    int rowt = ((lane >> 4) << 2) + j;
                    float nsv = fn[tt][j] + bn;
                    float uval = s_u[rowt * 64 + c];
                    float m = b2f(sread(s_x[cur], rowt, 64 + c));
                    if (!hi) {
                        float ymu = s_yo[rowt * 64 + c];
                        float ny = m * ((1.f - uval) * nsv + uval * ymu) + (1.f - m) * ymu;
                        s_ym[rowt * 64 + c] = ny;
                        hwrite(s_yc, rowt, c, ny);
                    } else {
                        float sold = s_sm[rowt * 64 + c];
                        float nstd = fabsf(nsv);
                        float nss = m * ((1.f - uval) * nstd + uval * sold) + (1.f - m) * sold;
                        nss = fabsf(nss);
                        s_sm[rowt * 64 + c] = nss;
                        hwrite(s_yc, rowt, 64 + c, nss);
                    }
                }
            }
        }
        __syncthreads();
    }

    // ---- Final: z = mlp2([y|s], tz) ----
    {
        f4 t1[2] = {zero4, zero4};
#pragma unroll
        for (int ks = 0; ks < 4; ++ks) {
            s8 a = aread(s_yc, lane, ks);
#pragma unroll
            for (int tt = 0; tt < 2; ++tt) t1[tt] = MFMA(a, wt1[tt][ks], t1[tt]);
        }
#pragma unroll
        for (int tt = 0; tt < 2; ++tt) {
            int colb = ((2 * w + tt) << 4) + (lane & 15);
            float bt = s_b[TB1 + colb];
#pragma unroll
            for (int j = 0; j < 4; ++j) {
                int rowt = ((lane >> 4) << 2) + j;
                hwrite(s_hA, rowt, colb, tanh_(t1[tt][j] + bt));
            }
        }
    }
    __syncthreads();
    {
        f4 t2[2] = {zero4, zero4};
#pragma unroll
        for (int ks = 0; ks < 4; ++ks) {
            s8 a = aread(s_hA, lane, ks);
#pragma unroll
            for (int tt = 0; tt < 2; ++tt) t2[tt] = MFMA(a, wt2[tt][ks], t2[tt]);
        }
#pragma unroll
        for (int tt = 0; tt < 2; ++tt) {
            int colf = ((2 * w + tt) << 4) + (lane & 15);
            float bt = s_b[TB2 + colf];
#pragma unroll
            for (int j = 0; j < 4; ++j) {
                int rowt = ((lane >> 4) << 2) + j;
                int gtraj = btraj + rowt;
                float z = t2[tt][j] + bt;
                size_t idx;
                float val;
                if (colf < 64) { idx = (size_t)gtraj * 64 + colf; val = z; }
                else { idx = (size_t)N_TRAJ * 64 + (size_t)gtraj * 64 + (colf - 64); val = fabsf(z); }
                if (isf32) ((float*)p.out)[idx] = val;
                else ((u16*)p.out)[idx] = f2b(val);
            }
        }
    }
}

extern "C" void kernel_launch(void* const* d_in, const int* in_sizes, int n_in,
                              void* d_out, int out_size, void* d_ws, size_t ws_size,
                              hipStream_t stream) {
    PackP pp;
    // order: ug_w1, rg_w1, ns_w1, ode_w1, ug_w2, rg_w2, ns_w2, ode_w2, tz_w1, tz_w2
    const int srcIdx[10] = {2, 6, 10, 14, 4, 8, 12, 16, 18, 20};
    const int Kr[10] = {256, 256, 256, 64, 100, 100, 100, 100, 128, 100};
    const int Nr[10] = {100, 100, 100, 100, 64, 64, 128, 64, 100, 128};
    const int KS[10] = {8, 8, 8, 2, 4, 4, 4, 4, 4, 4};
    const int NT[10] = {8, 8, 8, 8, 4, 4, 8, 4, 8, 8};
    for (int i = 0; i < 10; ++i) {
        pp.src[i] = d_in[srcIdx[i]];
        pp.Kr[i] = Kr[i];
        pp.Nr[i] = Nr[i];
        pp.KS[i] = KS[i];
        pp.sz[i] = KS[i] * NT[i] * 512;
    }
    pp.tps = d_in[1];
    repack_kernel<<<(PACK_ELEMS + 255) / 256, 256, 0, stream>>>(pp);

    PrepP bp;
    bp.tps = d_in[1];
    bp.ob1 = d_in[15]; bp.ob2 = d_in[17];
    bp.ub1 = d_in[3];  bp.ub2 = d_in[5];
    bp.rb1 = d_in[7];  bp.rb2 = d_in[9];
    bp.nb1 = d_in[11]; bp.nb2 = d_in[13];
    bp.tb1 = d_in[19]; bp.tb2 = d_in[21];
    prep_bias<<<1, 256, 0, stream>>>(bp);

    MainP mp;
    mp.data = d_in[0];
    mp.tps = d_in[1];
    mp.out = d_out;
    enc_main<<<N_TRAJ / 16, 256, 0, stream>>>(mp);
}

// Round 4
// 491.638 us; speedup vs baseline: 1.3179x; 1.3179x over previous
//
#include <hip/hip_runtime.h>

typedef unsigned short u16;
typedef __attribute__((ext_vector_type(8))) short s8;
typedef __attribute__((ext_vector_type(4))) short s4;
typedef __attribute__((ext_vector_type(4))) float f4;

#define N_TRAJ 4096
#define TSTEPS 128
#define LATD   64
#define INPD   128

// bias offsets (floats)
#define OB1 0
#define OB2 128
#define UB1 192
#define UB2 320
#define RB1 384
#define RB2 512
#define NB1 576
#define NB2 704
#define TB1 832
#define TB2 960
#define DTS 1088
#define NBIAS 1216

// packed weight offsets (elements)
#define OFF_UG1 0
#define OFF_RG1 32768
#define OFF_NS1 65536
#define OFF_OD1 98304
#define OFF_UG2 106496
#define OFF_RG2 114688
#define OFF_NS2 122880
#define OFF_OD2 139264
#define OFF_TZ1 147456
#define OFF_TZ2 163840
#define PACK_ELEMS 180224

__device__ u16 g_pack[PACK_ELEMS];
__device__ float g_bias[NBIAS];

__device__ __forceinline__ float b2f(u16 u) {
    union { unsigned int i; float f; } v; v.i = ((unsigned int)u) << 16; return v.f;
}
__device__ __forceinline__ u16 f2b(float f) {
    unsigned int x = __float_as_uint(f);
    unsigned int r = (x + 0x7FFFu + ((x >> 16) & 1u)) >> 16;
    return (u16)r;
}
__device__ __forceinline__ int is_f32(const void* tps) {
    return (*(const unsigned int*)tps) == 0u;  // f32: bits(0.0f)==0; bf16: u16 pair (0, 0x3C81) != 0
}
__device__ __forceinline__ float rdany(const void* a, int i, int isf32) {
    return isf32 ? ((const float*)a)[i] : b2f(((const u16*)a)[i]);
}
__device__ __forceinline__ float sigm(float x) {
    x = fminf(fmaxf(x, -30.f), 30.f);
    float e = __expf(-x);
    return __builtin_amdgcn_rcpf(1.f + e);
}
__device__ __forceinline__ float tanh_(float x) {
    x = fminf(fmaxf(x, -15.f), 15.f);
    float e = __expf(-2.f * x);
    return (1.f - e) * __builtin_amdgcn_rcpf(1.f + e);
}

// A-fragment read from a [16][128] bf16 LDS tile (row stride 256B, XOR swizzled)
__device__ __forceinline__ s8 aread(const u16* buf, int lane, int ks) {
    int row = lane & 15;
    int b = (ks << 6) + ((lane >> 4) << 4);
    int off = (row << 8) + (b ^ ((row & 7) << 4));
    return *(const s8*)((const char*)buf + off);
}
__device__ __forceinline__ void hwrite(u16* buf, int rowt, int col, float v) {
    int off = (rowt << 8) + (((col << 1)) ^ ((rowt & 7) << 4));
    *(u16*)((char*)buf + off) = f2b(v);
}
__device__ __forceinline__ u16 sread(const u16* buf, int rowt, int col) {
    int off = (rowt << 8) + (((col << 1)) ^ ((rowt & 7) << 4));
    return *(const u16*)((const char*)buf + off);
}
// load 4 consecutive x elements as bf16, from either dtype
__device__ __forceinline__ s4 load_x4(const void* data, size_t elemIdx, int isf32) {
    s4 r;
    if (isf32) {
        f4 v = *(const f4*)((const float*)data + elemIdx);
#pragma unroll
        for (int j = 0; j < 4; ++j) r[j] = (short)f2b(v[j]);
    } else {
        r = *(const s4*)((const u16*)data + elemIdx);
    }
    return r;
}

struct PackP {
    const void* src[10];
    const void* tps;
    int Kr[10], Nr[10], KS[10], sz[10];
};

__global__ __launch_bounds__(256) void repack_kernel(PackP p) {
    int gid = blockIdx.x * 256 + threadIdx.x;
    if (gid >= PACK_ELEMS) return;
    int isf32 = is_f32(p.tps);
    int idx = gid, m = 0, base = 0;
    while (m < 10 && idx >= p.sz[m]) { idx -= p.sz[m]; base += p.sz[m]; ++m; }
    if (m >= 10) return;
    int i = idx & 7;
    int l = (idx >> 3) & 63;
    int rest = idx >> 9;
    int ks = rest % p.KS[m];
    int nt = rest / p.KS[m];
    int k = ks * 32 + ((l >> 4) << 3) + i;
    int n = nt * 16 + (l & 15);
    u16 v = 0;
    if (k < p.Kr[m] && n < p.Nr[m]) v = f2b(rdany(p.src[m], k * p.Nr[m] + n, isf32));
    g_pack[base + idx] = v;
}

struct PrepP {
    const void *tps, *ob1, *ob2, *ub1, *ub2, *rb1, *rb2, *nb1, *nb2, *tb1, *tb2;
};

__global__ __launch_bounds__(256) void prep_bias(PrepP p) {
    int isf32 = is_f32(p.tps);
    int tid = threadIdx.x;
    for (int i = tid; i < 128; i += 256) {
        g_bias[OB1 + i] = (i < 100) ? rdany(p.ob1, i, isf32) : 0.f;
        g_bias[UB1 + i] = (i < 100) ? rdany(p.ub1, i, isf32) : 0.f;
        g_bias[RB1 + i] = (i < 100) ? rdany(p.rb1, i, isf32) : 0.f;
        g_bias[NB1 + i] = (i < 100) ? rdany(p.nb1, i, isf32) : 0.f;
        g_bias[TB1 + i] = (i < 100) ? rdany(p.tb1, i, isf32) : 0.f;
        g_bias[NB2 + i] = rdany(p.nb2, i, isf32);
        g_bias[TB2 + i] = rdany(p.tb2, i, isf32);
        g_bias[DTS + i] = (i == 0) ? -0.01f
                                   : (rdany(p.tps, 127 - i, isf32) - rdany(p.tps, 128 - i, isf32));
    }
    for (int i = tid; i < 64; i += 256) {
        g_bias[OB2 + i] = rdany(p.ob2, i, isf32);
        g_bias[UB2 + i] = rdany(p.ub2, i, isf32);
        g_bias[RB2 + i] = rdany(p.rb2, i, isf32);
    }
}

struct MainP {
    const void *data, *tps;
    void* out;
};

#define WLOAD(off, KSn, nt, ks) (*(const s8*)(pk + (off) + (((((nt) * (KSn)) + (ks)) << 6) + lane) * 8))
#define MFMA(a, b, c) __builtin_amdgcn_mfma_f32_16x16x32_bf16((a), (b), (c), 0, 0, 0)

__global__ __launch_bounds__(512, 2) void enc_main(MainP p) {
    __shared__ u16 s_x[2][2048];   // [16][128] bf16 swizzled, double buffered
    __shared__ u16 s_yc[2048];     // [y_mu | s] bf16 swizzled
    __shared__ u16 s_yc2[2048];    // [y_mu*r | s*r]
    __shared__ u16 s_hA[2048];     // h buffer (hode/hu/hns)
    __shared__ u16 s_hB[2048];     // hr
    __shared__ float s_ym[1024], s_yo[1024], s_sm[1024], s_u[1024];
    __shared__ float s_b[NBIAS];

    int tid = threadIdx.x, lane = tid & 63, w = tid >> 6;   // w = 0..7
    int btraj = blockIdx.x << 4;
    const u16* pk = g_pack;
    int isf32 = is_f32(p.tps);

    for (int i = tid; i < NBIAS; i += 512) s_b[i] = g_bias[i];
    for (int i = tid; i < 1024; i += 512) { s_ym[i] = 0.f; s_sm[i] = 0.f; }
    for (int i = tid; i < 2048; i += 512) s_yc[i] = 0;

    // per-wave weight fragments in registers: wave w owns N-tile nt=w for layer-1 nets
    s8 wl1u[8], wl1r[8], wl1n[8];   // K=256 nets: 8 k-slices each
    s8 wod1[2];                     // ODE layer1: K=64
    s8 w2x[4];                      // u2 (w<4, nt=w) or r2 (w>=4, nt=w-4)
    s8 wod2[4];                     // ODE layer2 (w<4 only)
    s8 wn2[4], wt1[4], wt2[4];
#pragma unroll
    for (int ks = 0; ks < 8; ++ks) {
        wl1u[ks] = WLOAD(OFF_UG1, 8, w, ks);
        wl1r[ks] = WLOAD(OFF_RG1, 8, w, ks);
        wl1n[ks] = WLOAD(OFF_NS1, 8, w, ks);
    }
    wod1[0] = WLOAD(OFF_OD1, 2, w, 0);
    wod1[1] = WLOAD(OFF_OD1, 2, w, 1);
#pragma unroll
    for (int ks = 0; ks < 4; ++ks) {
        wn2[ks] = WLOAD(OFF_NS2, 4, w, ks);
        wt1[ks] = WLOAD(OFF_TZ1, 4, w, ks);
        wt2[ks] = WLOAD(OFF_TZ2, 4, w, ks);
    }
    if (w < 4) {
#pragma unroll
        for (int ks = 0; ks < 4; ++ks) {
            w2x[ks] = WLOAD(OFF_UG2, 4, w, ks);
            wod2[ks] = WLOAD(OFF_OD2, 4, w, ks);
        }
    } else {
#pragma unroll
        for (int ks = 0; ks < 4; ++ks) w2x[ks] = WLOAD(OFF_RG2, 4, w - 4, ks);
    }

    // x prefetch: each of 512 threads owns 4 elems
    int xrow = tid >> 5, xk = tid & 31;
    int xoff = (xrow << 8) + ((xk << 3) ^ ((xrow & 7) << 4));
    {
        s4 xr = load_x4(p.data, ((size_t)(btraj + xrow) * TSTEPS + 127) * INPD + (xk << 2), isf32);
        *(s4*)((char*)s_x[0] + xoff) = xr;
    }
    __syncthreads();

    const f4 zero4 = {0.f, 0.f, 0.f, 0.f};
    int colw = (w << 4) + (lane & 15);       // this wave's output column (layer-1 style, 0..127)
    int rbase = (lane >> 4) << 2;            // first of 4 output rows

    for (int it = 0; it < TSTEPS; ++it) {
        int cur = it & 1;
        float dt = s_b[DTS + it];

        // prefetch next x (issue early; store in phase F)
        s4 xnext;
        if (it < 127) {
            xnext = load_x4(p.data, ((size_t)(btraj + xrow) * TSTEPS + (126 - it)) * INPD + (xk << 2), isf32);
        }

        // ---- Phase A: ODE layer 1 (A = y from yc[0:64], K=64), all 8 waves ----
        {
            f4 ao = zero4;
            ao = MFMA(aread(s_yc, lane, 0), wod1[0], ao);
            ao = MFMA(aread(s_yc, lane, 1), wod1[1], ao);
            float bias = s_b[OB1 + colw];
#pragma unroll
            for (int j = 0; j < 4; ++j)
                hwrite(s_hA, rbase + j, colw, tanh_(ao[j] + bias));
        }
        __syncthreads();

        // ---- Phase B: ODE layer 2 -> y_ode (waves 0-3) ----
        if (w < 4) {
            f4 ac = zero4;
#pragma unroll
            for (int ks = 0; ks < 4; ++ks) ac = MFMA(aread(s_hA, lane, ks), wod2[ks], ac);
            float bias = s_b[OB2 + colw];
#pragma unroll
            for (int j = 0; j < 4; ++j) {
                int rowt = rbase + j;
                float yo = s_ym[rowt * 64 + colw] + (ac[j] + bias) * dt;
                s_yo[rowt * 64 + colw] = yo;
                hwrite(s_yc, rowt, colw, yo);
            }
        }
        __syncthreads();

        // ---- Phase C: u,r layer 1 (A = [y_ode|s|x], K=256), all waves ----
        {
            f4 au = zero4, ar = zero4;
#pragma unroll
            for (int ks = 0; ks < 8; ++ks) {
                s8 a = (ks < 4) ? aread(s_yc, lane, ks) : aread(s_x[cur], lane, ks - 4);
                au = MFMA(a, wl1u[ks], au);
                ar = MFMA(a, wl1r[ks], ar);
            }
            float bu = s_b[UB1 + colw], br = s_b[RB1 + colw];
#pragma unroll
            for (int j = 0; j < 4; ++j) {
                int rowt = rbase + j;
                hwrite(s_hA, rowt, colw, tanh_(au[j] + bu));
                hwrite(s_hB, rowt, colw, tanh_(ar[j] + br));
            }
        }
        __syncthreads();

        // ---- Phase D: u2 (waves 0-3) / r2 + build yc2 (waves 4-7) ----
        if (w < 4) {
            f4 uac = zero4;
#pragma unroll
            for (int ks = 0; ks < 4; ++ks) uac = MFMA(aread(s_hA, lane, ks), w2x[ks], uac);
            float bu = s_b[UB2 + colw];
#pragma unroll
            for (int j = 0; j < 4; ++j)
                s_u[(rbase + j) * 64 + colw] = sigm(uac[j] + bu);
        } else {
            f4 rac = zero4;
#pragma unroll
            for (int ks = 0; ks < 4; ++ks) rac = MFMA(aread(s_hB, lane, ks), w2x[ks], rac);
            int col = colw - 64;
            float br = s_b[RB2 + col];
#pragma unroll
            for (int j = 0; j < 4; ++j) {
                int rowt = rbase + j;
                float rval = sigm(rac[j] + br);
                float ymu = s_yo[rowt * 64 + col];
                float sv = s_sm[rowt * 64 + col];
                hwrite(s_yc2, rowt, col, ymu * rval);
                hwrite(s_yc2, rowt, 64 + col, sv * rval);
            }
        }
        __syncthreads();

        // ---- Phase E: ns layer 1 (A = [yc2 | x], K=256), all waves ----
        {
            f4 an = zero4;
#pragma unroll
            for (int ks = 0; ks < 8; ++ks) {
                s8 a = (ks < 4) ? aread(s_yc2, lane, ks) : aread(s_x[cur], lane, ks - 4);
                an = MFMA(a, wl1n[ks], an);
            }
            float bn = s_b[NB1 + colw];
#pragma unroll
            for (int j = 0; j < 4; ++j)
                hwrite(s_hA, rbase + j, colw, tanh_(an[j] + bn));
        }
        __syncthreads();

        // ---- Phase F: ns layer 2 + state update, all waves ----
        {
            f4 fn = zero4;
#pragma unroll
            for (int ks = 0; ks < 4; ++ks) fn = MFMA(aread(s_hA, lane, ks), wn2[ks], fn);
            // store prefetched x into the other buffer
            if (it < 127) *(s4*)((char*)s_x[cur ^ 1] + xoff) = xnext;

            float bn = s_b[NB2 + colw];
            int c = colw & 63;
#pragma unroll
            for (int j = 0; j < 4; ++j) {
                int rowt = rbase + j;
                float nsv = fn[j] + bn;
                float uval = s_u[rowt * 64 + c];
                float m = b2f(sread(s_x[cur], rowt, 64 + c));
                if (w < 4) {
                    float ymu = s_yo[rowt * 64 + c];
                    float ny = m * ((1.f - uval) * nsv + uval * ymu) + (1.f - m) * ymu;
                    s_ym[rowt * 64 + c] = ny;
                    hwrite(s_yc, rowt, c, ny);
                } else {
                    float sold = s_sm[rowt * 64 + c];
                    float nstd = fabsf(nsv);
                    float nss = m * ((1.f - uval) * nstd + uval * sold) + (1.f - m) * sold;
                    nss = fabsf(nss);
                    s_sm[rowt * 64 + c] = nss;
                    hwrite(s_yc, rowt, 64 + c, nss);
                }
            }
        }
        __syncthreads();
    }

    // ---- Final: z = mlp2([y|s], tz) ----
    {
        f4 t1 = zero4;
#pragma unroll
        for (int ks = 0; ks < 4; ++ks) t1 = MFMA(aread(s_yc, lane, ks), wt1[ks], t1);
        float bt = s_b[TB1 + colw];
#pragma unroll
        for (int j = 0; j < 4; ++j)
            hwrite(s_hA, rbase + j, colw, tanh_(t1[j] + bt));
    }
    __syncthreads();
    {
        f4 t2 = zero4;
#pragma unroll
        for (int ks = 0; ks < 4; ++ks) t2 = MFMA(aread(s_hA, lane, ks), wt2[ks], t2);
        float bt = s_b[TB2 + colw];
#pragma unroll
        for (int j = 0; j < 4; ++j) {
            int gtraj = btraj + rbase + j;
            float z = t2[j] + bt;
            size_t idx;
            float val;
            if (colw < 64) { idx = (size_t)gtraj * 64 + colw; val = z; }
            else { idx = (size_t)N_TRAJ * 64 + (size_t)gtraj * 64 + (colw - 64); val = fabsf(z); }
            if (isf32) ((float*)p.out)[idx] = val;
            else ((u16*)p.out)[idx] = f2b(val);
        }
    }
}

extern "C" void kernel_launch(void* const* d_in, const int* in_sizes, int n_in,
                              void* d_out, int out_size, void* d_ws, size_t ws_size,
                              hipStream_t stream) {
    PackP pp;
    // order: ug_w1, rg_w1, ns_w1, ode_w1, ug_w2, rg_w2, ns_w2, ode_w2, tz_w1, tz_w2
    const int srcIdx[10] = {2, 6, 10, 14, 4, 8, 12, 16, 18, 20};
    const int Kr[10] = {256, 256, 256, 64, 100, 100, 100, 100, 128, 100};
    const int Nr[10] = {100, 100, 100, 100, 64, 64, 128, 64, 100, 128};
    const int KS[10] = {8, 8, 8, 2, 4, 4, 4, 4, 4, 4};
    const int NT[10] = {8, 8, 8, 8, 4, 4, 8, 4, 8, 8};
    for (int i = 0; i < 10; ++i) {
        pp.src[i] = d_in[srcIdx[i]];
        pp.Kr[i] = Kr[i];
        pp.Nr[i] = Nr[i];
        pp.KS[i] = KS[i];
        pp.sz[i] = KS[i] * NT[i] * 512;
    }
    pp.tps = d_in[1];
    repack_kernel<<<(PACK_ELEMS + 255) / 256, 256, 0, stream>>>(pp);

    PrepP bp;
    bp.tps = d_in[1];
    bp.ob1 = d_in[15]; bp.ob2 = d_in[17];
    bp.ub1 = d_in[3];  bp.ub2 = d_in[5];
    bp.rb1 = d_in[7];  bp.rb2 = d_in[9];
    bp.nb1 = d_in[11]; bp.nb2 = d_in[13];
    bp.tb1 = d_in[19]; bp.tb2 = d_in[21];
    prep_bias<<<1, 256, 0, stream>>>(bp);

    MainP mp;
    mp.data = d_in[0];
    mp.tps = d_in[1];
    mp.out = d_out;
    enc_main<<<N_TRAJ / 16, 512, 0, stream>>>(mp);
}

// Round 5
// 470.483 us; speedup vs baseline: 1.3772x; 1.0450x over previous
//
#include <hip/hip_runtime.h>

typedef unsigned short u16;
typedef __attribute__((ext_vector_type(8))) short s8;
typedef __attribute__((ext_vector_type(4))) short s4;
typedef __attribute__((ext_vector_type(4))) float f4;

#define N_TRAJ 4096
#define TSTEPS 128
#define LATD   64
#define INPD   128

// bias offsets (floats)
#define OB1 0
#define OB2 128
#define UB1 192
#define UB2 320
#define RB1 384
#define RB2 512
#define NB1 576
#define NB2 704
#define TB1 832
#define TB2 960
#define DTS 1088
#define NBIAS 1216

// packed weight offsets (elements)
#define OFF_UG1 0
#define OFF_RG1 32768
#define OFF_NS1 65536
#define OFF_OD1 98304
#define OFF_UG2 106496
#define OFF_RG2 114688
#define OFF_NS2 122880
#define OFF_OD2 139264
#define OFF_TZ1 147456
#define OFF_TZ2 163840
#define PACK_ELEMS 180224

__device__ u16 g_pack[PACK_ELEMS];
__device__ float g_bias[NBIAS];

__device__ __forceinline__ float b2f(u16 u) {
    union { unsigned int i; float f; } v; v.i = ((unsigned int)u) << 16; return v.f;
}
__device__ __forceinline__ u16 f2b(float f) {
    unsigned int x = __float_as_uint(f);
    unsigned int r = (x + 0x7FFFu + ((x >> 16) & 1u)) >> 16;
    return (u16)r;
}
__device__ __forceinline__ int is_f32(const void* tps) {
    return (*(const unsigned int*)tps) == 0u;  // f32: bits(0.0f)==0; bf16: u16 pair (0, 0x3C81) != 0
}
__device__ __forceinline__ float rdany(const void* a, int i, int isf32) {
    return isf32 ? ((const float*)a)[i] : b2f(((const u16*)a)[i]);
}
__device__ __forceinline__ float sigm(float x) {
    x = fminf(fmaxf(x, -30.f), 30.f);
    float e = __expf(-x);
    return __builtin_amdgcn_rcpf(1.f + e);
}
__device__ __forceinline__ float tanh_(float x) {
    x = fminf(fmaxf(x, -15.f), 15.f);
    float e = __expf(-2.f * x);
    return (1.f - e) * __builtin_amdgcn_rcpf(1.f + e);
}

// A-fragment read from a [16][128] bf16 LDS tile (row stride 256B, XOR swizzled)
__device__ __forceinline__ s8 aread(const u16* buf, int lane, int ks) {
    int row = lane & 15;
    int b = (ks << 6) + ((lane >> 4) << 4);
    int off = (row << 8) + (b ^ ((row & 7) << 4));
    return *(const s8*)((const char*)buf + off);
}
__device__ __forceinline__ void hwrite(u16* buf, int rowt, int col, float v) {
    int off = (rowt << 8) + (((col << 1)) ^ ((rowt & 7) << 4));
    *(u16*)((char*)buf + off) = f2b(v);
}
__device__ __forceinline__ u16 sread(const u16* buf, int rowt, int col) {
    int off = (rowt << 8) + (((col << 1)) ^ ((rowt & 7) << 4));
    return *(const u16*)((const char*)buf + off);
}
// load 4 consecutive x elements as bf16, from either dtype
__device__ __forceinline__ s4 load_x4(const void* data, size_t elemIdx, int isf32) {
    s4 r;
    if (isf32) {
        f4 v = *(const f4*)((const float*)data + elemIdx);
#pragma unroll
        for (int j = 0; j < 4; ++j) r[j] = (short)f2b(v[j]);
    } else {
        r = *(const s4*)((const u16*)data + elemIdx);
    }
    return r;
}

struct PackP {
    const void* src[10];
    const void* tps;
    int Kr[10], Nr[10], KS[10], sz[10];
};

__global__ __launch_bounds__(256) void repack_kernel(PackP p) {
    int gid = blockIdx.x * 256 + threadIdx.x;
    if (gid >= PACK_ELEMS) return;
    int isf32 = is_f32(p.tps);
    int idx = gid, m = 0, base = 0;
    while (m < 10 && idx >= p.sz[m]) { idx -= p.sz[m]; base += p.sz[m]; ++m; }
    if (m >= 10) return;
    int i = idx & 7;
    int l = (idx >> 3) & 63;
    int rest = idx >> 9;
    int ks = rest % p.KS[m];
    int nt = rest / p.KS[m];
    int k = ks * 32 + ((l >> 4) << 3) + i;
    int n = nt * 16 + (l & 15);
    u16 v = 0;
    if (k < p.Kr[m] && n < p.Nr[m]) v = f2b(rdany(p.src[m], k * p.Nr[m] + n, isf32));
    g_pack[base + idx] = v;
}

struct PrepP {
    const void *tps, *ob1, *ob2, *ub1, *ub2, *rb1, *rb2, *nb1, *nb2, *tb1, *tb2;
};

__global__ __launch_bounds__(256) void prep_bias(PrepP p) {
    int isf32 = is_f32(p.tps);
    int tid = threadIdx.x;
    for (int i = tid; i < 128; i += 256) {
        g_bias[OB1 + i] = (i < 100) ? rdany(p.ob1, i, isf32) : 0.f;
        g_bias[UB1 + i] = (i < 100) ? rdany(p.ub1, i, isf32) : 0.f;
        g_bias[RB1 + i] = (i < 100) ? rdany(p.rb1, i, isf32) : 0.f;
        g_bias[NB1 + i] = (i < 100) ? rdany(p.nb1, i, isf32) : 0.f;
        g_bias[TB1 + i] = (i < 100) ? rdany(p.tb1, i, isf32) : 0.f;
        g_bias[NB2 + i] = rdany(p.nb2, i, isf32);
        g_bias[TB2 + i] = rdany(p.tb2, i, isf32);
        g_bias[DTS + i] = (i == 0) ? -0.01f
                                   : (rdany(p.tps, 127 - i, isf32) - rdany(p.tps, 128 - i, isf32));
    }
    for (int i = tid; i < 64; i += 256) {
        g_bias[OB2 + i] = rdany(p.ob2, i, isf32);
        g_bias[UB2 + i] = rdany(p.ub2, i, isf32);
        g_bias[RB2 + i] = rdany(p.rb2, i, isf32);
    }
}

struct MainP {
    const void *data, *tps;
    void* out;
};

#define WLOAD(off, KSn, nt, ks) (*(const s8*)(pk + (off) + (((((nt) * (KSn)) + (ks)) << 6) + lane) * 8))
#define MFMA(a, b, c) __builtin_amdgcn_mfma_f32_16x16x32_bf16((a), (b), (c), 0, 0, 0)

__global__ __launch_bounds__(512, 2) void enc_main(MainP p) {
    __shared__ u16 s_x[2][2048];   // [16][128] bf16 swizzled, double buffered
    __shared__ u16 s_yc[2048];     // [y_mu | s] bf16 swizzled
    __shared__ u16 s_yc2[2048];    // [y_mu*r | s*r]
    __shared__ u16 s_hA[2048];     // h buffer (hode/hu/hns)
    __shared__ u16 s_hB[2048];     // hr
    __shared__ float s_yo[16 * 65];  // y_ode, stride 65 (conflict-free)
    __shared__ float s_u[16 * 65];   // update gate, stride 65
    __shared__ float s_b[NBIAS];

    int tid = threadIdx.x, lane = tid & 63, w = tid >> 6;   // w = 0..7
    int btraj = blockIdx.x << 4;
    const u16* pk = g_pack;
    int isf32 = is_f32(p.tps);

    for (int i = tid; i < NBIAS; i += 512) s_b[i] = g_bias[i];
    for (int i = tid; i < 2048; i += 512) s_yc[i] = 0;

    // persistent per-wave layer-1 weight fragments (nt = w)
    s8 wl1u[8], wl1r[8], wl1n[8];   // K=256 nets: 8 k-slices each
    s8 wod1[2];                     // ODE layer1: K=64
#pragma unroll
    for (int ks = 0; ks < 8; ++ks) {
        wl1u[ks] = WLOAD(OFF_UG1, 8, w, ks);
        wl1r[ks] = WLOAD(OFF_RG1, 8, w, ks);
        wl1n[ks] = WLOAD(OFF_NS1, 8, w, ks);
    }
    wod1[0] = WLOAD(OFF_OD1, 2, w, 0);
    wod1[1] = WLOAD(OFF_OD1, 2, w, 1);

    // register-resident recurrent state:
    //  waves 0-3: ymu_r (y_mu), yo_r (y_ode), u_r (update gate) at col=colw
    //  waves 4-7: s_r (y_std) at col=colw-64
    f4 ymu_r = {0.f, 0.f, 0.f, 0.f};
    f4 s_r = {0.f, 0.f, 0.f, 0.f};
    f4 yo_r = {0.f, 0.f, 0.f, 0.f};
    f4 u_r = {0.f, 0.f, 0.f, 0.f};

    // x prefetch: each of 512 threads owns 4 elems
    int xrow = tid >> 5, xk = tid & 31;
    int xoff = (xrow << 8) + ((xk << 3) ^ ((xrow & 7) << 4));
    {
        s4 xr = load_x4(p.data, ((size_t)(btraj + xrow) * TSTEPS + 127) * INPD + (xk << 2), isf32);
        *(s4*)((char*)s_x[0] + xoff) = xr;
    }
    __syncthreads();

    const f4 zero4 = {0.f, 0.f, 0.f, 0.f};
    int colw = (w << 4) + (lane & 15);       // this wave's output column (0..127)
    int rbase = (lane >> 4) << 2;            // first of 4 output rows

    for (int it = 0; it < TSTEPS; ++it) {
        int cur = it & 1;
        float dt = s_b[DTS + it];

        // prefetch next x (issue early; store in phase F)
        s4 xnext;
        if (it < 127) {
            xnext = load_x4(p.data, ((size_t)(btraj + xrow) * TSTEPS + (126 - it)) * INPD + (xk << 2), isf32);
        }

        // accumulators for u1/r1, built up across phases A and C
        f4 au = zero4, ar = zero4;

        // ---- Phase A: ODE layer 1 + u1/r1 partials over s (ks2,3) and x (ks4-7) ----
        {
            f4 ao = zero4;
            ao = MFMA(aread(s_yc, lane, 0), wod1[0], ao);
            ao = MFMA(aread(s_yc, lane, 1), wod1[1], ao);
#pragma unroll
            for (int ks = 2; ks < 4; ++ks) {
                s8 a = aread(s_yc, lane, ks);
                au = MFMA(a, wl1u[ks], au);
                ar = MFMA(a, wl1r[ks], ar);
            }
#pragma unroll
            for (int ks = 0; ks < 4; ++ks) {
                s8 a = aread(s_x[cur], lane, ks);
                au = MFMA(a, wl1u[4 + ks], au);
                ar = MFMA(a, wl1r[4 + ks], ar);
            }
            float bias = s_b[OB1 + colw];
#pragma unroll
            for (int j = 0; j < 4; ++j)
                hwrite(s_hA, rbase + j, colw, tanh_(ao[j] + bias));
        }
        __syncthreads();

        // ---- Phase B: ODE layer 2 -> y_ode (waves 0-3) ----
        if (w < 4) {
            s8 wod2[4];
#pragma unroll
            for (int ks = 0; ks < 4; ++ks) wod2[ks] = WLOAD(OFF_OD2, 4, w, ks);
            f4 ac = zero4;
#pragma unroll
            for (int ks = 0; ks < 4; ++ks) ac = MFMA(aread(s_hA, lane, ks), wod2[ks], ac);
            float bias = s_b[OB2 + colw];
#pragma unroll
            for (int j = 0; j < 4; ++j) {
                int rowt = rbase + j;
                float yo = ymu_r[j] + (ac[j] + bias) * dt;
                yo_r[j] = yo;
                s_yo[rowt * 65 + colw] = yo;
                hwrite(s_yc, rowt, colw, yo);
            }
        }
        __syncthreads();

        // ---- Phase C: u1/r1 finish with y_ode part (ks0,1) ----
        {
#pragma unroll
            for (int ks = 0; ks < 2; ++ks) {
                s8 a = aread(s_yc, lane, ks);
                au = MFMA(a, wl1u[ks], au);
                ar = MFMA(a, wl1r[ks], ar);
            }
            float bu = s_b[UB1 + colw], br = s_b[RB1 + colw];
#pragma unroll
            for (int j = 0; j < 4; ++j) {
                int rowt = rbase + j;
                hwrite(s_hA, rowt, colw, tanh_(au[j] + bu));
                hwrite(s_hB, rowt, colw, tanh_(ar[j] + br));
            }
        }
        __syncthreads();

        // ---- Phase D: u2 (waves 0-3) / r2 + build yc2 (waves 4-7) ----
        if (w < 4) {
            s8 w2[4];
#pragma unroll
            for (int ks = 0; ks < 4; ++ks) w2[ks] = WLOAD(OFF_UG2, 4, w, ks);
            f4 uac = zero4;
#pragma unroll
            for (int ks = 0; ks < 4; ++ks) uac = MFMA(aread(s_hA, lane, ks), w2[ks], uac);
            float bu = s_b[UB2 + colw];
#pragma unroll
            for (int j = 0; j < 4; ++j) {
                float uv = sigm(uac[j] + bu);
                u_r[j] = uv;
                s_u[(rbase + j) * 65 + colw] = uv;
            }
        } else {
            s8 w2[4];
#pragma unroll
            for (int ks = 0; ks < 4; ++ks) w2[ks] = WLOAD(OFF_RG2, 4, w - 4, ks);
            f4 rac = zero4;
#pragma unroll
            for (int ks = 0; ks < 4; ++ks) rac = MFMA(aread(s_hB, lane, ks), w2[ks], rac);
            int col = colw - 64;
            float br = s_b[RB2 + col];
#pragma unroll
            for (int j = 0; j < 4; ++j) {
                int rowt = rbase + j;
                float rval = sigm(rac[j] + br);
                float yo = s_yo[rowt * 65 + col];
                hwrite(s_yc2, rowt, col, yo * rval);
                hwrite(s_yc2, rowt, 64 + col, s_r[j] * rval);
            }
        }
        __syncthreads();

        // ---- Phase E: ns layer 1 (A = [yc2 | x], K=256), all waves ----
        {
            f4 an = zero4;
#pragma unroll
            for (int ks = 0; ks < 4; ++ks) an = MFMA(aread(s_yc2, lane, ks), wl1n[ks], an);
#pragma unroll
            for (int ks = 0; ks < 4; ++ks) an = MFMA(aread(s_x[cur], lane, ks), wl1n[4 + ks], an);
            float bn = s_b[NB1 + colw];
#pragma unroll
            for (int j = 0; j < 4; ++j)
                hwrite(s_hA, rbase + j, colw, tanh_(an[j] + bn));
        }
        __syncthreads();

        // ---- Phase F: ns layer 2 + state update, all waves ----
        {
            s8 wn2[4];
#pragma unroll
            for (int ks = 0; ks < 4; ++ks) wn2[ks] = WLOAD(OFF_NS2, 4, w, ks);
            f4 fn = zero4;
#pragma unroll
            for (int ks = 0; ks < 4; ++ks) fn = MFMA(aread(s_hA, lane, ks), wn2[ks], fn);
            // store prefetched x into the other buffer
            if (it < 127) *(s4*)((char*)s_x[cur ^ 1] + xoff) = xnext;

            float bn = s_b[NB2 + colw];
            int c = colw & 63;
#pragma unroll
            for (int j = 0; j < 4; ++j) {
                int rowt = rbase + j;
                float nsv = fn[j] + bn;
                float m = b2f(sread(s_x[cur], rowt, 64 + c));
                if (w < 4) {
                    float mg = m * (1.f - u_r[j]);
                    float ny = yo_r[j] + mg * (nsv - yo_r[j]);
                    ymu_r[j] = ny;
                    hwrite(s_yc, rowt, c, ny);
                } else {
                    float uval = s_u[rowt * 65 + c];
                    float mg = m * (1.f - uval);
                    float nstd = fabsf(nsv);
                    float nss = s_r[j] + mg * (nstd - s_r[j]);
                    nss = fabsf(nss);
                    s_r[j] = nss;
                    hwrite(s_yc, rowt, 64 + c, nss);
                }
            }
        }
        __syncthreads();
    }

    // ---- Final: z = mlp2([y|s], tz) ----
    s8 wt1[4], wt2[4];
#pragma unroll
    for (int ks = 0; ks < 4; ++ks) {
        wt1[ks] = WLOAD(OFF_TZ1, 4, w, ks);
        wt2[ks] = WLOAD(OFF_TZ2, 4, w, ks);
    }
    {
        f4 t1 = zero4;
#pragma unroll
        for (int ks = 0; ks < 4; ++ks) t1 = MFMA(aread(s_yc, lane, ks), wt1[ks], t1);
        float bt = s_b[TB1 + colw];
#pragma unroll
        for (int j = 0; j < 4; ++j)
            hwrite(s_hA, rbase + j, colw, tanh_(t1[j] + bt));
    }
    __syncthreads();
    {
        f4 t2 = zero4;
#pragma unroll
        for (int ks = 0; ks < 4; ++ks) t2 = MFMA(aread(s_hA, lane, ks), wt2[ks], t2);
        float bt = s_b[TB2 + colw];
#pragma unroll
        for (int j = 0; j < 4; ++j) {
            int gtraj = btraj + rbase + j;
            float z = t2[j] + bt;
            size_t idx;
            float val;
            if (colw < 64) { idx = (size_t)gtraj * 64 + colw; val = z; }
            else { idx = (size_t)N_TRAJ * 64 + (size_t)gtraj * 64 + (colw - 64); val = fabsf(z); }
            if (isf32) ((float*)p.out)[idx] = val;
            else ((u16*)p.out)[idx] = f2b(val);
        }
    }
}

extern "C" void kernel_launch(void* const* d_in, const int* in_sizes, int n_in,
                              void* d_out, int out_size, void* d_ws, size_t ws_size,
                              hipStream_t stream) {
    PackP pp;
    // order: ug_w1, rg_w1, ns_w1, ode_w1, ug_w2, rg_w2, ns_w2, ode_w2, tz_w1, tz_w2
    const int srcIdx[10] = {2, 6, 10, 14, 4, 8, 12, 16, 18, 20};
    const int Kr[10] = {256, 256, 256, 64, 100, 100, 100, 100, 128, 100};
    const int Nr[10] = {100, 100, 100, 100, 64, 64, 128, 64, 100, 128};
    const int KS[10] = {8, 8, 8, 2, 4, 4, 4, 4, 4, 4};
    const int NT[10] = {8, 8, 8, 8, 4, 4, 8, 4, 8, 8};
    for (int i = 0; i < 10; ++i) {
        pp.src[i] = d_in[srcIdx[i]];
        pp.Kr[i] = Kr[i];
        pp.Nr[i] = Nr[i];
        pp.KS[i] = KS[i];
        pp.sz[i] = KS[i] * NT[i] * 512;
    }
    pp.tps = d_in[1];
    repack_kernel<<<(PACK_ELEMS + 255) / 256, 256, 0, stream>>>(pp);

    PrepP bp;
    bp.tps = d_in[1];
    bp.ob1 = d_in[15]; bp.ob2 = d_in[17];
    bp.ub1 = d_in[3];  bp.ub2 = d_in[5];
    bp.rb1 = d_in[7];  bp.rb2 = d_in[9];
    bp.nb1 = d_in[11]; bp.nb2 = d_in[13];
    bp.tb1 = d_in[19]; bp.tb2 = d_in[21];
    prep_bias<<<1, 256, 0, stream>>>(bp);

    MainP mp;
    mp.data = d_in[0];
    mp.tps = d_in[1];
    mp.out = d_out;
    enc_main<<<N_TRAJ / 16, 512, 0, stream>>>(mp);
}